// Round 14
// baseline (363.119 us; speedup 1.0000x reference)
//
#include <hip/hip_runtime.h>
#include <hip/hip_bf16.h>
#include <stdint.h>

// Problem constants (reference: T=10, N=2048, E=32768, H=256)
#define TT 10
#define NN 2048
#define EE 32768
#define HH 256

typedef short bf16x8 __attribute__((ext_vector_type(8)));
typedef float f32x4 __attribute__((ext_vector_type(4)));

__device__ __forceinline__ float b2f(unsigned short u) {
    unsigned int x = ((unsigned int)u) << 16;
    return __builtin_bit_cast(float, x);
}
__device__ __forceinline__ unsigned short f2b(float f) {
    unsigned int x = __builtin_bit_cast(unsigned int, f);
    unsigned int r = x + 0x7FFFu + ((x >> 16) & 1u);
    return (unsigned short)(r >> 16);
}

#define GLOAD_LDS16(g, l)                                                      \
    __builtin_amdgcn_global_load_lds(                                          \
        (const __attribute__((address_space(1))) void*)(g),                    \
        (__attribute__((address_space(3))) void*)(l), 16, 0, 0)

// ---------------- setup kernels ----------------

__global__ void cvt_bf16_kernel(const float* __restrict__ in,
                                unsigned short* __restrict__ out, int n) {
    int i = blockIdx.x * blockDim.x + threadIdx.x;
    int stride = gridDim.x * blockDim.x;
    for (; i < n; i += stride) out[i] = f2b(in[i]);
}

// All weight transposes + bias512 in one dispatch.
// We1 [528][256] -> Wabt [512][256] (out 0..255 = We1 k0..255; out 256..511 =
// We1 k256..511), Wrt [256][32] (k 512..527 live, rest 0).
__global__ void transpose_all_kernel(
    const float* __restrict__ We1, const float* __restrict__ We2,
    const float* __restrict__ Wn1, const float* __restrict__ Wn2,
    const float* __restrict__ Wc1, const float* __restrict__ be1,
    unsigned short* __restrict__ Wabt, unsigned short* __restrict__ Wrt,
    unsigned short* __restrict__ We2t, unsigned short* __restrict__ Wn1t,
    unsigned short* __restrict__ Wn2t, unsigned short* __restrict__ Wc1t,
    float* __restrict__ bias512) {
    int idx = blockIdx.x * blockDim.x + threadIdx.x;
    const int s1 = 131072;           // Wabt [512][256]
    const int s2 = s1 + 8192;        // Wrt  [256][32]
    const int s3 = s2 + 65536;       // We2t [256][256]
    const int s4 = s3 + 196608;      // Wn1t [256][768]
    const int s5 = s4 + 65536;       // Wn2t [256][256]
    const int s6 = s5 + 65536;       // Wc1t [256][256]
    const int s7 = s6 + 512;         // bias512
    if (idx >= s7) return;
    if (idx < s1) {
        int li = idx, n = li >> 8, k = li & 255;   // n: 0..511 output col
        int krow = (n < 256) ? k : (256 + k);
        int col = n & 255;
        Wabt[li] = f2b(We1[krow * 256 + col]);
    } else if (idx < s2) {
        int li = idx - s1, n = li >> 5, k = li & 31;
        Wrt[li] = (k < 16) ? f2b(We1[(512 + k) * 256 + n]) : (unsigned short)0;
    } else if (idx < s3) {
        int li = idx - s2, n = li >> 8, k = li & 255;
        We2t[li] = f2b(We2[k * 256 + n]);
    } else if (idx < s4) {
        int li = idx - s3, n = li / 768, k = li - n * 768;
        Wn1t[li] = f2b(Wn1[k * 256 + n]);
    } else if (idx < s5) {
        int li = idx - s4, n = li >> 8, k = li & 255;
        Wn2t[li] = f2b(Wn2[k * 256 + n]);
    } else if (idx < s6) {
        int li = idx - s5, n = li >> 8, k = li & 255;
        Wc1t[li] = f2b(Wc1[k * 256 + n]);
    } else {
        int li = idx - s6;
        bias512[li] = (li < 256) ? be1[li] : 0.0f;
    }
}

__global__ void zero_f32_kernel(float* __restrict__ p, int n) {
    int i = blockIdx.x * blockDim.x + threadIdx.x;
    int stride = gridDim.x * blockDim.x;
    for (; i < n; i += stride) p[i] = 0.0f;
}

__global__ void count_kernel(const int* __restrict__ rows, int* __restrict__ counts) {
    int e = blockIdx.x * blockDim.x + threadIdx.x;
    if (e < EE) atomicAdd(&counts[rows[e]], 1);
}

// Exclusive scan of counts[0..2047] -> boff[0..2048]. One block, 256 threads.
__global__ __launch_bounds__(256) void scan_kernel(const int* __restrict__ counts,
                                                   int* __restrict__ boff) {
    __shared__ int part[256];
    int tid = threadIdx.x;
    int base = tid * 8;
    int local[8];
    int s = 0;
#pragma unroll
    for (int i = 0; i < 8; ++i) { local[i] = s; s += counts[base + i]; }
    part[tid] = s;
    __syncthreads();
    for (int offd = 1; offd < 256; offd <<= 1) {
        int v = (tid >= offd) ? part[tid - offd] : 0;
        __syncthreads();
        part[tid] += v;
        __syncthreads();
    }
    int pbase = (tid == 0) ? 0 : part[tid - 1];
#pragma unroll
    for (int i = 0; i < 8; ++i) boff[base + i] = pbase + local[i];
    if (tid == 255) boff[2048] = pbase + s;
}

// Scatter edges into row-sorted order: rs[pos]=row, cs[pos]=col.
__global__ void scatter_kernel(const int* __restrict__ rows, const int* __restrict__ cols,
                               const int* __restrict__ boff, int* __restrict__ cursor,
                               int* __restrict__ rs, int* __restrict__ cs) {
    int e = blockIdx.x * blockDim.x + threadIdx.x;
    if (e < EE) {
        int r = rows[e];
        int pos = boff[r] + atomicAdd(&cursor[r], 1);
        rs[pos] = r;
        cs[pos] = cols[e];
    }
}

// ---------------- edge megakernel helpers ----------------

// BK=64 B-stage (r7-proven): [256][64] rows with 16B-slot source swizzle.
__device__ __forceinline__ void stageB64(const unsigned short* __restrict__ Wt,
                                         int KPAD, int k0, int tid, int w,
                                         unsigned short* Bs) {
    int trow = tid >> 3;
    int sk8 = ((tid & 7) ^ (trow & 7)) * 8;
#pragma unroll
    for (int i = 0; i < 8; ++i) {
        int row = i * 32 + trow;
        GLOAD_LDS16(Wt + (size_t)row * KPAD + k0 + sk8, Bs + i * 2048 + w * 512);
    }
}

__device__ __forceinline__ void mfma_step_es(const unsigned short* Es,
                                             const unsigned short* Bs, int k0,
                                             int w, int lr, int lq, f32x4 acc[4][4]) {
    int xs = (lr & 7) << 3;
#pragma unroll
    for (int kk = 0; kk < 64; kk += 32) {
        bf16x8 a[4], b[4];
        int lcol = kk + lq * 8;
#pragma unroll
        for (int m = 0; m < 4; ++m)
            a[m] = *reinterpret_cast<const bf16x8*>(
                Es + (m * 16 + lr) * 256 + ((k0 + lcol) ^ xs));
#pragma unroll
        for (int n = 0; n < 4; ++n)
            b[n] = *reinterpret_cast<const bf16x8*>(
                Bs + (w * 64 + n * 16 + lr) * 64 + (lcol ^ xs));
#pragma unroll
        for (int m = 0; m < 4; ++m)
#pragma unroll
            for (int n = 0; n < 4; ++n)
                acc[m][n] = __builtin_amdgcn_mfma_f32_16x16x32_bf16(
                    a[m], b[n], acc[m][n], 0, 0, 0);
    }
}

// ---------------- edge megakernel ----------------
// Per block: 64 SORTED edge-instances. Phases:
//  0) radial + cdiff (4 threads/edge) -> LDS (CDs, Rs)
//  1) acc = radial@Wrt^T (K=32 step)
//  1e) acc += yab[rs][col] / yab[cs][256+col] via LDS-staged passes; relu -> Es
//  2) E2 = relu(E1 @ We2t^T + be2)                K=256, BK=64 -> Es
//  3) m  = relu(E2 @ Wc1t^T + bc1) . Wc2          K=256, BK=64 -> Ms
//  epilogue: node-boundary-flush agg (Es) and csum (CDs*m) atomics.
__global__ __launch_bounds__(256, 2) void edge_mega_kernel(
    const float* __restrict__ x, const unsigned short* __restrict__ yab,
    const unsigned short* __restrict__ Wrt,
    const unsigned short* __restrict__ We2t, const float* __restrict__ be2,
    const unsigned short* __restrict__ Wc1t, const float* __restrict__ bc1,
    const float* __restrict__ Wc2,
    const int* __restrict__ rs, const int* __restrict__ cs,
    float* __restrict__ aggf, float* __restrict__ csum) {
    __shared__ unsigned short As[64 * 32];    // 4 KB
    __shared__ unsigned short Bs[256 * 64];   // 32 KB (also yab-stage buffer)
    __shared__ unsigned short Es[64 * 256];   // 32 KB (swizzled)
    __shared__ float CDs[64][12];             // 3 KB
    __shared__ unsigned short Rs[64][16];     // 2 KB
    __shared__ float Ms[64][4];               // 1 KB

    int tid = threadIdx.x;
    int lane = tid & 63, w = tid >> 6;
    int lr = lane & 15, lq = lane >> 4;
    int blockRow = blockIdx.x * 64;
    int tt = blockRow >> 15;                  // uniform timestep per block
    int sb = blockRow & (EE - 1);             // base sorted-index

    // ---- phase 0: radial + cdiff, 4 threads per edge ----
    {
        int el = tid >> 2, j = tid & 3;
        int s = sb + el;
        int r = rs[s], c = cs[s];
        const float* xr = x + ((size_t)tt * NN + r) * 12;
        const float* xc = x + ((size_t)tt * NN + c) * 12;
        float cd[12];
#pragma unroll
        for (int i = 0; i < 12; ++i) cd[i] = xr[i] - xc[i];
#pragma unroll
        for (int d = 0; d < 3; ++d) CDs[el][j * 3 + d] = cd[j * 3 + d];
        float g4[4], ss = 0.f;
#pragma unroll
        for (int k = 0; k < 4; ++k) {
            float v = cd[j * 3] * cd[k * 3] + cd[j * 3 + 1] * cd[k * 3 + 1] +
                      cd[j * 3 + 2] * cd[k * 3 + 2];
            g4[k] = v;
            ss += v * v;
        }
        ss += __shfl_xor(ss, 1);
        ss += __shfl_xor(ss, 2);
        float inv = 1.f / fmaxf(sqrtf(ss), 1e-12f);
#pragma unroll
        for (int k = 0; k < 4; ++k) Rs[el][j * 4 + k] = f2b(g4[k] * inv);
    }

    int srow = tid >> 2, sslot = tid & 3;     // BK=32 staging geometry (r11)
    int xoff32 = (sslot ^ ((srow >> 1) & 3)) * 8;
    int axoff = (lq ^ ((lr >> 1) & 3)) * 8;

    __syncthreads();  // Rs/CDs ready

    f32x4 acc[4][4];
#pragma unroll
    for (int m = 0; m < 4; ++m)
#pragma unroll
        for (int n = 0; n < 4; ++n) acc[m][n] = (f32x4){0.f, 0.f, 0.f, 0.f};

    // ---- phase 1: radial @ Wrt, single K=32 step (cols 0..15 live) ----
    {
        // As[64][32] from Rs (swizzled placement, r11-proven)
        int ls = sslot ^ ((srow >> 1) & 3);
        bf16x8 v = {};
        if (ls < 2) {
#pragma unroll
            for (int ii = 0; ii < 8; ++ii) v[ii] = (short)Rs[srow][ls * 8 + ii];
        }
        *reinterpret_cast<bf16x8*>(As + tid * 8) = v;
        // Bs[256][32] from Wrt (4 gloads/thread, r11-proven)
#pragma unroll
        for (int i = 0; i < 4; ++i)
            GLOAD_LDS16(Wrt + (size_t)(i * 64 + srow) * 32 + xoff32,
                        Bs + i * 2048 + w * 512);
        __syncthreads();
        bf16x8 a[4], b[4];
#pragma unroll
        for (int m = 0; m < 4; ++m)
            a[m] = *reinterpret_cast<const bf16x8*>(
                As + (m * 16 + lr) * 32 + axoff);
#pragma unroll
        for (int n = 0; n < 4; ++n)
            b[n] = *reinterpret_cast<const bf16x8*>(
                Bs + (w * 64 + n * 16 + lr) * 32 + axoff);
#pragma unroll
        for (int m = 0; m < 4; ++m)
#pragma unroll
            for (int n = 0; n < 4; ++n)
                acc[m][n] = __builtin_amdgcn_mfma_f32_16x16x32_bf16(
                    a[m], b[n], acc[m][n], 0, 0, 0);
        __syncthreads();   // all waves done reading Bs -> reusable
    }

    // ---- epi1a: acc += yab rows, staged through Bs via per-lane gload_lds ----
    // Bs reused as [64][256] bf16 (exactly 32 KB). Stage swizzle: 16B slot
    // ^= (row>>2)&3 so the read (lq stride-4 rows) is bank-clean.
#pragma unroll 1
    for (int pass = 0; pass < 2; ++pass) {
        const int* idx = pass ? cs : rs;
        int halfoff = pass ? 256 : 0;
#pragma unroll
        for (int i = 0; i < 8; ++i) {
            int row2 = (i * 4 + w) * 2 + (lane >> 5);      // wave-issue covers 2 rows
            int node = idx[sb + row2];
            int slot = (lane & 31) ^ ((row2 >> 2) & 3);
            GLOAD_LDS16(yab + ((size_t)tt * NN + node) * 512 + halfoff + slot * 8,
                        Bs + (i * 4 + w) * 512);
        }
        __syncthreads();   // stage complete (vmcnt drained by barrier)
#pragma unroll
        for (int m = 0; m < 4; ++m)
#pragma unroll
            for (int r = 0; r < 4; ++r) {
                int row = m * 16 + lq * 4 + r;
                int sw = ((row >> 2) & 3) << 3;
#pragma unroll
                for (int n = 0; n < 4; ++n) {
                    int col = w * 64 + n * 16 + lr;
                    acc[m][n][r] += b2f(Bs[row * 256 + (col ^ sw)]);
                }
            }
        __syncthreads();   // reads done before next overwrite of Bs
    }
    {   // epi1b: relu -> Es (swizzled)
#pragma unroll
        for (int m = 0; m < 4; ++m)
#pragma unroll
            for (int r = 0; r < 4; ++r) {
                int row = m * 16 + lq * 4 + r;
                int xsw = (row & 7) << 3;
#pragma unroll
                for (int n = 0; n < 4; ++n) {
                    int col = w * 64 + n * 16 + lr;
                    float v = fmaxf(acc[m][n][r], 0.f);
                    Es[row * 256 + (col ^ xsw)] = f2b(v);
                }
            }
    }
    __syncthreads();

    // ---- phase 2: E2 = relu(E1 @ We2t^T + be2) ----
#pragma unroll
    for (int m = 0; m < 4; ++m)
#pragma unroll
        for (int n = 0; n < 4; ++n) acc[m][n] = (f32x4){0.f, 0.f, 0.f, 0.f};
#pragma unroll 1
    for (int k0 = 0; k0 < 256; k0 += 64) {
        stageB64(We2t, 256, k0, tid, w, Bs);
        __syncthreads();
        mfma_step_es(Es, Bs, k0, w, lr, lq, acc);
        __syncthreads();
    }
    {   // epilogue 2: overwrite Es with E2
        float bv[4];
#pragma unroll
        for (int n = 0; n < 4; ++n) bv[n] = be2[w * 64 + n * 16 + lr];
#pragma unroll
        for (int m = 0; m < 4; ++m)
#pragma unroll
            for (int r = 0; r < 4; ++r) {
                int row = m * 16 + lq * 4 + r;
                int xsw = (row & 7) << 3;
#pragma unroll
                for (int n = 0; n < 4; ++n) {
                    int col = w * 64 + n * 16 + lr;
                    float v = fmaxf(acc[m][n][r] + bv[n], 0.f);
                    Es[row * 256 + (col ^ xsw)] = f2b(v);
                }
            }
    }
    __syncthreads();

    // ---- phase 3: m = relu(E2 @ Wc1t^T + bc1) . Wc2 ----
#pragma unroll
    for (int m = 0; m < 4; ++m)
#pragma unroll
        for (int n = 0; n < 4; ++n) acc[m][n] = (f32x4){0.f, 0.f, 0.f, 0.f};
#pragma unroll 1
    for (int k0 = 0; k0 < 256; k0 += 64) {
        stageB64(Wc1t, 256, k0, tid, w, Bs);
        __syncthreads();
        mfma_step_es(Es, Bs, k0, w, lr, lq, acc);
        __syncthreads();
    }
    {   // epilogue 3: per-row dot with Wc2, 16-lane reduce, cross-wave via Ms
        float bv[4], wv[4];
#pragma unroll
        for (int n = 0; n < 4; ++n) {
            int col = w * 64 + n * 16 + lr;
            bv[n] = bc1[col];
            wv[n] = Wc2[col];
        }
#pragma unroll
        for (int m = 0; m < 4; ++m)
#pragma unroll
            for (int r = 0; r < 4; ++r) {
                float p = 0.f;
#pragma unroll
                for (int n = 0; n < 4; ++n)
                    p += fmaxf(acc[m][n][r] + bv[n], 0.f) * wv[n];
                p += __shfl_xor(p, 1);
                p += __shfl_xor(p, 2);
                p += __shfl_xor(p, 4);
                p += __shfl_xor(p, 8);
                if (lr == 0) Ms[m * 16 + lq * 4 + r][w] = p;
            }
    }
    __syncthreads();

    if (tid < 64) {   // fold per-row m into Ms[.][0]
        Ms[tid][0] = Ms[tid][0] + Ms[tid][1] + Ms[tid][2] + Ms[tid][3];
    }
    __syncthreads();

    // ---- agg: rows sorted by node -> boundary-flush (low-contention atomics) ----
    {
        float accv = 0.f;
        for (int i = 0; i < 64; ++i) {
            int ncur = rs[sb + i];          // uniform scalar load
            accv += b2f(Es[i * 256 + (tid ^ ((i & 7) << 3))]);
            if (i == 63 || rs[sb + i + 1] != ncur) {
                atomicAdd(&aggf[((size_t)tt * NN + ncur) * 256 + tid], accv);
                accv = 0.f;
            }
        }
    }
    // ---- csum: same boundary-flush over CDs * m ----
    if (tid < 12) {
        float a = 0.f;
        for (int i = 0; i < 64; ++i) {
            int ncur = rs[sb + i];
            a += CDs[i][tid] * Ms[i][0];
            if (i == 63 || rs[sb + i + 1] != ncur) {
                atomicAdd(&csum[((size_t)tt * NN + ncur) * 12 + tid], a);
                a = 0.f;
            }
        }
    }
}

// ---------------- node GEMM (m97 128x128, BK=32) ----------------
// EPI 0: relu -> bf16 store (ldc 256).
// EPI 2: f32 store outf = acc + bias + resid (ldc 256).
// EPI 3: bf16 store, NO relu, ldc 512 (Yab producer).
template<int EPI>
__global__ __launch_bounds__(256) void gemm_kernel(
    const unsigned short* __restrict__ A, const unsigned short* __restrict__ Wt,
    const float* __restrict__ bias, unsigned short* __restrict__ Cb, int KPAD,
    const float* __restrict__ resid, float* __restrict__ outf) {
    __shared__ unsigned short As[128 * 32];
    __shared__ unsigned short Bs[128 * 32];
    int tid = threadIdx.x;
    int lane = tid & 63, w = tid >> 6;
    int wr = w >> 1, wc = w & 1;
    int blockRow = blockIdx.x * 128, colBase = blockIdx.y * 128;
    int l4 = lane >> 2;
    int seg = lane & 3;

    int ar0 = blockRow + w * 16 + l4;
    int br0 = colBase + w * 16 + l4;
    const unsigned short* pA0 = A + (size_t)ar0 * KPAD + seg * 8;
    const unsigned short* pA1 = pA0 + (size_t)64 * KPAD;
    const unsigned short* pB0 = Wt + (size_t)br0 * KPAD + seg * 8;
    const unsigned short* pB1 = pB0 + (size_t)64 * KPAD;

    unsigned short* ldsA = As + w * 512;
    unsigned short* ldsB = Bs + w * 512;

    f32x4 acc[4][4] = {};
    int lr = lane & 15, lq = lane >> 4;

    for (int k0 = 0; k0 < KPAD; k0 += 32) {
        GLOAD_LDS16(pA0 + k0, ldsA);
        GLOAD_LDS16(pA1 + k0, ldsA + 2048);
        GLOAD_LDS16(pB0 + k0, ldsB);
        GLOAD_LDS16(pB1 + k0, ldsB + 2048);
        __syncthreads();
        bf16x8 a[4], b[4];
#pragma unroll
        for (int m = 0; m < 4; ++m)
            a[m] = *reinterpret_cast<const bf16x8*>(
                As + (wr * 64 + m * 16 + lr) * 32 + lq * 8);
#pragma unroll
        for (int n = 0; n < 4; ++n)
            b[n] = *reinterpret_cast<const bf16x8*>(
                Bs + (wc * 64 + n * 16 + lr) * 32 + lq * 8);
#pragma unroll
        for (int m = 0; m < 4; ++m)
#pragma unroll
            for (int n = 0; n < 4; ++n)
                acc[m][n] = __builtin_amdgcn_mfma_f32_16x16x32_bf16(
                    a[m], b[n], acc[m][n], 0, 0, 0);
        __syncthreads();
    }

    float bv[4];
#pragma unroll
    for (int n = 0; n < 4; ++n) bv[n] = bias[colBase + wc * 64 + n * 16 + lr];

#pragma unroll
    for (int m = 0; m < 4; ++m)
#pragma unroll
        for (int r = 0; r < 4; ++r) {
            int row = blockRow + wr * 64 + m * 16 + lq * 4 + r;
#pragma unroll
            for (int n = 0; n < 4; ++n) {
                int col = colBase + wc * 64 + n * 16 + lr;
                float v = acc[m][n][r] + bv[n];
                if (EPI == 2) {
                    outf[(size_t)row * 256 + col] =
                        v + resid[(size_t)row * 256 + col];
                } else if (EPI == 3) {
                    Cb[(size_t)row * 512 + col] = f2b(v);
                } else {
                    Cb[(size_t)row * 256 + col] = f2b(fmaxf(v, 0.f));
                }
            }
        }
}

// node_in[nf][768] = [others(256 f32), h(256 bf16), agg(256 f32)] as bf16
__global__ void nodein_kernel(const float* __restrict__ others,
                              const unsigned short* __restrict__ hb,
                              const float* __restrict__ aggf,
                              unsigned short* __restrict__ node_in) {
    int idx = blockIdx.x * blockDim.x + threadIdx.x;
    int stride = gridDim.x * blockDim.x;
    const int total = TT * NN * 192;
    for (; idx < total; idx += stride) {
        int nf = idx / 192, c4 = (idx - nf * 192) * 4;
        ushort4 v;
        if (c4 < 256) {
            float4 o = *reinterpret_cast<const float4*>(others + (size_t)nf * 256 + c4);
            v.x = f2b(o.x); v.y = f2b(o.y); v.z = f2b(o.z); v.w = f2b(o.w);
        } else if (c4 < 512) {
            v = *reinterpret_cast<const ushort4*>(hb + (size_t)nf * 256 + (c4 - 256));
        } else {
            float4 a = *reinterpret_cast<const float4*>(aggf + (size_t)nf * 256 + (c4 - 512));
            v.x = f2b(a.x); v.y = f2b(a.y); v.z = f2b(a.z); v.w = f2b(a.w);
        }
        *reinterpret_cast<ushort4*>(node_in + (size_t)nf * 768 + c4) = v;
    }
}

__global__ void coordout_kernel(const float* __restrict__ x, const int* __restrict__ counts,
                                const float* __restrict__ csum, float* __restrict__ outc) {
    int idx = blockIdx.x * blockDim.x + threadIdx.x;
    if (idx >= TT * NN * 12) return;
    int n = (idx / 12) & (NN - 1);
    float cnt = (float)(counts[n] > 0 ? counts[n] : 1);
    outc[idx] = x[idx] + csum[idx] / cnt;
}

// ---------------- launch ----------------

extern "C" void kernel_launch(void* const* d_in, const int* in_sizes, int n_in,
                              void* d_out, int out_size, void* d_ws, size_t ws_size,
                              hipStream_t stream) {
    const float* x = (const float*)d_in[0];
    const float* h = (const float*)d_in[1];
    const float* others = (const float*)d_in[2];
    const float* We1 = (const float*)d_in[3];
    const float* be1 = (const float*)d_in[4];
    const float* We2 = (const float*)d_in[5];
    const float* be2 = (const float*)d_in[6];
    const float* Wn1 = (const float*)d_in[7];
    const float* bn1 = (const float*)d_in[8];
    const float* Wn2 = (const float*)d_in[9];
    const float* bn2 = (const float*)d_in[10];
    const float* Wc1 = (const float*)d_in[11];
    const float* bc1 = (const float*)d_in[12];
    const float* Wc2 = (const float*)d_in[13];
    const int* ei = (const int*)d_in[14];
    const int* rows = ei;
    const int* cols = ei + EE;

    char* wsb = (char*)d_ws;
    size_t off = 0;
    auto alloc = [&](size_t bytes) {
        void* p = wsb + off;
        off = (off + bytes + 255) & ~(size_t)255;
        return p;
    };
    const int TNH = TT * NN * HH;
    unsigned short* hb = (unsigned short*)alloc((size_t)TNH * 2);
    unsigned short* Wabt = (unsigned short*)alloc(512 * 256 * 2);
    unsigned short* Wrt = (unsigned short*)alloc(256 * 32 * 2);
    unsigned short* We2t = (unsigned short*)alloc(256 * 256 * 2);
    unsigned short* Wn1t = (unsigned short*)alloc(256 * 768 * 2);
    unsigned short* Wn2t = (unsigned short*)alloc(256 * 256 * 2);
    unsigned short* Wc1t = (unsigned short*)alloc(256 * 256 * 2);
    float* bias512 = (float*)alloc(512 * 4);
    unsigned short* yab = (unsigned short*)alloc((size_t)TT * NN * 512 * 2);  // 21 MB
    float* aggf = (float*)alloc((size_t)TT * NN * 256 * 4);  // contiguous zero region:
    float* csum = (float*)alloc((size_t)TT * NN * 12 * 4);   // aggf | csum
    int* counts = (int*)alloc((size_t)2048 * 4);   // counts | cursor (zeroed together)
    int* cursor = (int*)alloc((size_t)2048 * 4);
    int* boff = (int*)alloc((size_t)2049 * 4);
    int* rs = (int*)alloc((size_t)EE * 4);
    int* cs = (int*)alloc((size_t)EE * 4);
    unsigned short* node_in = (unsigned short*)alloc((size_t)TT * NN * 768 * 2);
    unsigned short* Z = (unsigned short*)alloc((size_t)TT * NN * 256 * 2);
    (void)ws_size;

    // ---- setup ----
    cvt_bf16_kernel<<<2048, 256, 0, stream>>>(h, hb, TNH);
    transpose_all_kernel<<<2082, 256, 0, stream>>>(
        We1, We2, Wn1, Wn2, Wc1, be1, Wabt, Wrt, We2t, Wn1t, Wn2t, Wc1t, bias512);
    zero_f32_kernel<<<16, 256, 0, stream>>>((float*)counts, 4096);  // counts+cursor
    count_kernel<<<EE / 256, 256, 0, stream>>>(rows, counts);
    scan_kernel<<<1, 256, 0, stream>>>(counts, boff);
    scatter_kernel<<<EE / 256, 256, 0, stream>>>(rows, cols, boff, cursor, rs, cs);
    zero_f32_kernel<<<2048, 256, 0, stream>>>(aggf, TT * NN * 256 + TT * NN * 12);

    float* houtf = (float*)d_out;
    float* coutf = (float*)d_out + (size_t)TT * NN * HH;

    // ---- Yab = h @ [We1a|We1b] + [be1|0]  -> bf16 [20480][512] ----
    gemm_kernel<3><<<dim3(TT * NN / 128, 4), 256, 0, stream>>>(
        hb, Wabt, bias512, yab, 256, nullptr, nullptr);

    // ---- fused edge pipeline: all T, sorted edges, CSR epilogues ----
    edge_mega_kernel<<<TT * EE / 64, 256, 0, stream>>>(
        x, yab, Wrt, We2t, be2, Wc1t, bc1, Wc2, rs, cs, aggf, csum);

    // ---- node pipeline ----
    nodein_kernel<<<2048, 256, 0, stream>>>(others, hb, aggf, node_in);
    gemm_kernel<0><<<dim3(TT * NN / 128, 2), 256, 0, stream>>>(
        node_in, Wn1t, bn1, Z, 768, nullptr, nullptr);
    gemm_kernel<2><<<dim3(TT * NN / 128, 2), 256, 0, stream>>>(
        Z, Wn2t, bn2, nullptr, 256, h, houtf);

    coordout_kernel<<<(TT * NN * 12 + 255) / 256, 256, 0, stream>>>(
        x, counts, csum, coutf);
}

// Round 15
// 346.990 us; speedup vs baseline: 1.0465x; 1.0465x over previous
//
#include <hip/hip_runtime.h>
#include <hip/hip_bf16.h>
#include <stdint.h>

// Problem constants (reference: T=10, N=2048, E=32768, H=256)
#define TT 10
#define NN 2048
#define EE 32768
#define HH 256

typedef short bf16x8 __attribute__((ext_vector_type(8)));
typedef float f32x4 __attribute__((ext_vector_type(4)));

__device__ __forceinline__ float b2f(unsigned short u) {
    unsigned int x = ((unsigned int)u) << 16;
    return __builtin_bit_cast(float, x);
}
__device__ __forceinline__ unsigned short f2b(float f) {
    unsigned int x = __builtin_bit_cast(unsigned int, f);
    unsigned int r = x + 0x7FFFu + ((x >> 16) & 1u);
    return (unsigned short)(r >> 16);
}

#define GLOAD_LDS16(g, l)                                                      \
    __builtin_amdgcn_global_load_lds(                                          \
        (const __attribute__((address_space(1))) void*)(g),                    \
        (__attribute__((address_space(3))) void*)(l), 16, 0, 0)

// ---------------- setup kernels ----------------

// h -> hb and others -> ob in one launch.
__global__ void cvt2_bf16_kernel(const float* __restrict__ h,
                                 const float* __restrict__ others,
                                 unsigned short* __restrict__ hb,
                                 unsigned short* __restrict__ ob, int n) {
    int i = blockIdx.x * blockDim.x + threadIdx.x;
    int stride = gridDim.x * blockDim.x;
    for (; i < n; i += stride) {
        hb[i] = f2b(h[i]);
        ob[i] = f2b(others[i]);
    }
}

__global__ void cvt_bf16_kernel(const float* __restrict__ in,
                                unsigned short* __restrict__ out, int n) {
    int i = blockIdx.x * blockDim.x + threadIdx.x;
    int stride = gridDim.x * blockDim.x;
    for (; i < n; i += stride) out[i] = f2b(in[i]);
}

// All weight transposes + bias512 in one dispatch.
// We1 [528][256] -> Wabt [512][256] (out 0..255 = We1 k0..255; out 256..511 =
// We1 k256..511), Wrt [256][32] (k 512..527 live, rest 0).
__global__ void transpose_all_kernel(
    const float* __restrict__ We1, const float* __restrict__ We2,
    const float* __restrict__ Wn1, const float* __restrict__ Wn2,
    const float* __restrict__ Wc1, const float* __restrict__ be1,
    unsigned short* __restrict__ Wabt, unsigned short* __restrict__ Wrt,
    unsigned short* __restrict__ We2t, unsigned short* __restrict__ Wn1t,
    unsigned short* __restrict__ Wn2t, unsigned short* __restrict__ Wc1t,
    float* __restrict__ bias512) {
    int idx = blockIdx.x * blockDim.x + threadIdx.x;
    const int s1 = 131072;           // Wabt [512][256]
    const int s2 = s1 + 8192;        // Wrt  [256][32]
    const int s3 = s2 + 65536;       // We2t [256][256]
    const int s4 = s3 + 196608;      // Wn1t [256][768]
    const int s5 = s4 + 65536;       // Wn2t [256][256]
    const int s6 = s5 + 65536;       // Wc1t [256][256]
    const int s7 = s6 + 512;         // bias512
    if (idx >= s7) return;
    if (idx < s1) {
        int li = idx, n = li >> 8, k = li & 255;   // n: 0..511 output col
        int krow = (n < 256) ? k : (256 + k);
        int col = n & 255;
        Wabt[li] = f2b(We1[krow * 256 + col]);
    } else if (idx < s2) {
        int li = idx - s1, n = li >> 5, k = li & 31;
        Wrt[li] = (k < 16) ? f2b(We1[(512 + k) * 256 + n]) : (unsigned short)0;
    } else if (idx < s3) {
        int li = idx - s2, n = li >> 8, k = li & 255;
        We2t[li] = f2b(We2[k * 256 + n]);
    } else if (idx < s4) {
        int li = idx - s3, n = li / 768, k = li - n * 768;
        Wn1t[li] = f2b(Wn1[k * 256 + n]);
    } else if (idx < s5) {
        int li = idx - s4, n = li >> 8, k = li & 255;
        Wn2t[li] = f2b(Wn2[k * 256 + n]);
    } else if (idx < s6) {
        int li = idx - s5, n = li >> 8, k = li & 255;
        Wc1t[li] = f2b(Wc1[k * 256 + n]);
    } else {
        int li = idx - s6;
        bias512[li] = (li < 256) ? be1[li] : 0.0f;
    }
}

__global__ void zero_f32_kernel(float* __restrict__ p, int n) {
    int i = blockIdx.x * blockDim.x + threadIdx.x;
    int stride = gridDim.x * blockDim.x;
    for (; i < n; i += stride) p[i] = 0.0f;
}

__global__ void count_kernel(const int* __restrict__ rows, int* __restrict__ counts) {
    int e = blockIdx.x * blockDim.x + threadIdx.x;
    if (e < EE) atomicAdd(&counts[rows[e]], 1);
}

// Exclusive scan of counts[0..2047] -> boff[0..2048]. One block, 256 threads.
__global__ __launch_bounds__(256) void scan_kernel(const int* __restrict__ counts,
                                                   int* __restrict__ boff) {
    __shared__ int part[256];
    int tid = threadIdx.x;
    int base = tid * 8;
    int local[8];
    int s = 0;
#pragma unroll
    for (int i = 0; i < 8; ++i) { local[i] = s; s += counts[base + i]; }
    part[tid] = s;
    __syncthreads();
    for (int offd = 1; offd < 256; offd <<= 1) {
        int v = (tid >= offd) ? part[tid - offd] : 0;
        __syncthreads();
        part[tid] += v;
        __syncthreads();
    }
    int pbase = (tid == 0) ? 0 : part[tid - 1];
#pragma unroll
    for (int i = 0; i < 8; ++i) boff[base + i] = pbase + local[i];
    if (tid == 255) boff[2048] = pbase + s;
}

// Scatter edges into row-sorted order: rs[pos]=row, cs[pos]=col.
__global__ void scatter_kernel(const int* __restrict__ rows, const int* __restrict__ cols,
                               const int* __restrict__ boff, int* __restrict__ cursor,
                               int* __restrict__ rs, int* __restrict__ cs) {
    int e = blockIdx.x * blockDim.x + threadIdx.x;
    if (e < EE) {
        int r = rows[e];
        int pos = boff[r] + atomicAdd(&cursor[r], 1);
        rs[pos] = r;
        cs[pos] = cols[e];
    }
}

// ---------------- edge megakernel helpers ----------------

// BK=64 B-stage (r7-proven): [256][64] rows with 16B-slot source swizzle.
__device__ __forceinline__ void stageB64(const unsigned short* __restrict__ Wt,
                                         int KPAD, int k0, int tid, int w,
                                         unsigned short* Bs) {
    int trow = tid >> 3;
    int sk8 = ((tid & 7) ^ (trow & 7)) * 8;
#pragma unroll
    for (int i = 0; i < 8; ++i) {
        int row = i * 32 + trow;
        GLOAD_LDS16(Wt + (size_t)row * KPAD + k0 + sk8, Bs + i * 2048 + w * 512);
    }
}

__device__ __forceinline__ void mfma_step_es(const unsigned short* Es,
                                             const unsigned short* Bs, int k0,
                                             int w, int lr, int lq, f32x4 acc[4][4]) {
    int xs = (lr & 7) << 3;
#pragma unroll
    for (int kk = 0; kk < 64; kk += 32) {
        bf16x8 a[4], b[4];
        int lcol = kk + lq * 8;
#pragma unroll
        for (int m = 0; m < 4; ++m)
            a[m] = *reinterpret_cast<const bf16x8*>(
                Es + (m * 16 + lr) * 256 + ((k0 + lcol) ^ xs));
#pragma unroll
        for (int n = 0; n < 4; ++n)
            b[n] = *reinterpret_cast<const bf16x8*>(
                Bs + (w * 64 + n * 16 + lr) * 64 + (lcol ^ xs));
#pragma unroll
        for (int m = 0; m < 4; ++m)
#pragma unroll
            for (int n = 0; n < 4; ++n)
                acc[m][n] = __builtin_amdgcn_mfma_f32_16x16x32_bf16(
                    a[m], b[n], acc[m][n], 0, 0, 0);
    }
}

// ---------------- edge megakernel (r13 verbatim) ----------------
// Per block: 64 SORTED edge-instances. Phases:
//  0) radial + cdiff (4 threads/edge) -> LDS (CDs, Rs)
//  1) E1 = relu(radial@Wrt^T + yab[rs][col] + yab[cs][256+col])  (K=32 step)
//  2) E2 = relu(E1 @ We2t^T + be2)                K=256, BK=64 -> Es
//  3) m  = relu(E2 @ Wc1t^T + bc1) . Wc2          K=256, BK=64 -> Ms
//  epilogue: node-boundary-flush agg (Es) and csum (CDs*m) atomics.
__global__ __launch_bounds__(256, 2) void edge_mega_kernel(
    const float* __restrict__ x, const unsigned short* __restrict__ yab,
    const unsigned short* __restrict__ Wrt,
    const unsigned short* __restrict__ We2t, const float* __restrict__ be2,
    const unsigned short* __restrict__ Wc1t, const float* __restrict__ bc1,
    const float* __restrict__ Wc2,
    const int* __restrict__ rs, const int* __restrict__ cs,
    float* __restrict__ aggf, float* __restrict__ csum) {
    __shared__ unsigned short As[64 * 32];    // 4 KB
    __shared__ unsigned short Bs[256 * 64];   // 32 KB
    __shared__ unsigned short Es[64 * 256];   // 32 KB (swizzled)
    __shared__ float CDs[64][12];             // 3 KB
    __shared__ unsigned short Rs[64][16];     // 2 KB
    __shared__ float Ms[64][4];               // 1 KB

    int tid = threadIdx.x;
    int lane = tid & 63, w = tid >> 6;
    int lr = lane & 15, lq = lane >> 4;
    int blockRow = blockIdx.x * 64;
    int tt = blockRow >> 15;                  // uniform timestep per block
    int sb = blockRow & (EE - 1);             // base sorted-index

    // ---- phase 0: radial + cdiff, 4 threads per edge ----
    {
        int el = tid >> 2, j = tid & 3;
        int s = sb + el;
        int r = rs[s], c = cs[s];
        const float* xr = x + ((size_t)tt * NN + r) * 12;
        const float* xc = x + ((size_t)tt * NN + c) * 12;
        float cd[12];
#pragma unroll
        for (int i = 0; i < 12; ++i) cd[i] = xr[i] - xc[i];
#pragma unroll
        for (int d = 0; d < 3; ++d) CDs[el][j * 3 + d] = cd[j * 3 + d];
        float g4[4], ss = 0.f;
#pragma unroll
        for (int k = 0; k < 4; ++k) {
            float v = cd[j * 3] * cd[k * 3] + cd[j * 3 + 1] * cd[k * 3 + 1] +
                      cd[j * 3 + 2] * cd[k * 3 + 2];
            g4[k] = v;
            ss += v * v;
        }
        ss += __shfl_xor(ss, 1);
        ss += __shfl_xor(ss, 2);
        float inv = 1.f / fmaxf(sqrtf(ss), 1e-12f);
#pragma unroll
        for (int k = 0; k < 4; ++k) Rs[el][j * 4 + k] = f2b(g4[k] * inv);
    }

    int srow = tid >> 2, sslot = tid & 3;     // BK=32 staging geometry (r11)
    int xoff32 = (sslot ^ ((srow >> 1) & 3)) * 8;
    int axoff = (lq ^ ((lr >> 1) & 3)) * 8;

    __syncthreads();  // Rs/CDs ready

    f32x4 acc[4][4];
#pragma unroll
    for (int m = 0; m < 4; ++m)
#pragma unroll
        for (int n = 0; n < 4; ++n) acc[m][n] = (f32x4){0.f, 0.f, 0.f, 0.f};

    // ---- phase 1: radial @ Wrt, single K=32 step (cols 0..15 live) ----
    {
        // As[64][32] from Rs (swizzled placement, r11-proven)
        int ls = sslot ^ ((srow >> 1) & 3);
        bf16x8 v = {};
        if (ls < 2) {
#pragma unroll
            for (int ii = 0; ii < 8; ++ii) v[ii] = (short)Rs[srow][ls * 8 + ii];
        }
        *reinterpret_cast<bf16x8*>(As + tid * 8) = v;
        // Bs[256][32] from Wrt (4 gloads/thread, r11-proven)
#pragma unroll
        for (int i = 0; i < 4; ++i)
            GLOAD_LDS16(Wrt + (size_t)(i * 64 + srow) * 32 + xoff32,
                        Bs + i * 2048 + w * 512);
        __syncthreads();
        bf16x8 a[4], b[4];
#pragma unroll
        for (int m = 0; m < 4; ++m)
            a[m] = *reinterpret_cast<const bf16x8*>(
                As + (m * 16 + lr) * 32 + axoff);
#pragma unroll
        for (int n = 0; n < 4; ++n)
            b[n] = *reinterpret_cast<const bf16x8*>(
                Bs + (w * 64 + n * 16 + lr) * 32 + axoff);
#pragma unroll
        for (int m = 0; m < 4; ++m)
#pragma unroll
            for (int n = 0; n < 4; ++n)
                acc[m][n] = __builtin_amdgcn_mfma_f32_16x16x32_bf16(
                    a[m], b[n], acc[m][n], 0, 0, 0);
        __syncthreads();
    }
    {   // epilogue 1: E1 = relu(acc + yab[rs][col] + yab[cs][256+col]) -> Es
#pragma unroll
        for (int m = 0; m < 4; ++m)
#pragma unroll
            for (int r = 0; r < 4; ++r) {
                int row = m * 16 + lq * 4 + r;
                int e = sb + row;
                const unsigned short* pa = yab + ((size_t)tt * NN + rs[e]) * 512;
                const unsigned short* pb = yab + ((size_t)tt * NN + cs[e]) * 512 + 256;
                int xsw = (row & 7) << 3;
#pragma unroll
                for (int n = 0; n < 4; ++n) {
                    int col = w * 64 + n * 16 + lr;
                    float v = fmaxf(acc[m][n][r] + b2f(pa[col]) + b2f(pb[col]), 0.f);
                    Es[row * 256 + (col ^ xsw)] = f2b(v);
                }
            }
    }
    __syncthreads();

    // ---- phase 2: E2 = relu(E1 @ We2t^T + be2) ----
#pragma unroll
    for (int m = 0; m < 4; ++m)
#pragma unroll
        for (int n = 0; n < 4; ++n) acc[m][n] = (f32x4){0.f, 0.f, 0.f, 0.f};
#pragma unroll 1
    for (int k0 = 0; k0 < 256; k0 += 64) {
        stageB64(We2t, 256, k0, tid, w, Bs);
        __syncthreads();
        mfma_step_es(Es, Bs, k0, w, lr, lq, acc);
        __syncthreads();
    }
    {   // epilogue 2: overwrite Es with E2
        float bv[4];
#pragma unroll
        for (int n = 0; n < 4; ++n) bv[n] = be2[w * 64 + n * 16 + lr];
#pragma unroll
        for (int m = 0; m < 4; ++m)
#pragma unroll
            for (int r = 0; r < 4; ++r) {
                int row = m * 16 + lq * 4 + r;
                int xsw = (row & 7) << 3;
#pragma unroll
                for (int n = 0; n < 4; ++n) {
                    int col = w * 64 + n * 16 + lr;
                    float v = fmaxf(acc[m][n][r] + bv[n], 0.f);
                    Es[row * 256 + (col ^ xsw)] = f2b(v);
                }
            }
    }
    __syncthreads();

    // ---- phase 3: m = relu(E2 @ Wc1t^T + bc1) . Wc2 ----
#pragma unroll
    for (int m = 0; m < 4; ++m)
#pragma unroll
        for (int n = 0; n < 4; ++n) acc[m][n] = (f32x4){0.f, 0.f, 0.f, 0.f};
#pragma unroll 1
    for (int k0 = 0; k0 < 256; k0 += 64) {
        stageB64(Wc1t, 256, k0, tid, w, Bs);
        __syncthreads();
        mfma_step_es(Es, Bs, k0, w, lr, lq, acc);
        __syncthreads();
    }
    {   // epilogue 3: per-row dot with Wc2, 16-lane reduce, cross-wave via Ms
        float bv[4], wv[4];
#pragma unroll
        for (int n = 0; n < 4; ++n) {
            int col = w * 64 + n * 16 + lr;
            bv[n] = bc1[col];
            wv[n] = Wc2[col];
        }
#pragma unroll
        for (int m = 0; m < 4; ++m)
#pragma unroll
            for (int r = 0; r < 4; ++r) {
                float p = 0.f;
#pragma unroll
                for (int n = 0; n < 4; ++n)
                    p += fmaxf(acc[m][n][r] + bv[n], 0.f) * wv[n];
                p += __shfl_xor(p, 1);
                p += __shfl_xor(p, 2);
                p += __shfl_xor(p, 4);
                p += __shfl_xor(p, 8);
                if (lr == 0) Ms[m * 16 + lq * 4 + r][w] = p;
            }
    }
    __syncthreads();

    if (tid < 64) {   // fold per-row m into Ms[.][0]
        Ms[tid][0] = Ms[tid][0] + Ms[tid][1] + Ms[tid][2] + Ms[tid][3];
    }
    __syncthreads();

    // ---- agg: rows sorted by node -> boundary-flush (low-contention atomics) ----
    {
        float accv = 0.f;
        for (int i = 0; i < 64; ++i) {
            int ncur = rs[sb + i];          // uniform scalar load
            accv += b2f(Es[i * 256 + (tid ^ ((i & 7) << 3))]);
            if (i == 63 || rs[sb + i + 1] != ncur) {
                atomicAdd(&aggf[((size_t)tt * NN + ncur) * 256 + tid], accv);
                accv = 0.f;
            }
        }
    }
    // ---- csum: same boundary-flush over CDs * m ----
    if (tid < 12) {
        float a = 0.f;
        for (int i = 0; i < 64; ++i) {
            int ncur = rs[sb + i];
            a += CDs[i][tid] * Ms[i][0];
            if (i == 63 || rs[sb + i + 1] != ncur) {
                atomicAdd(&csum[((size_t)tt * NN + ncur) * 12 + tid], a);
                a = 0.f;
            }
        }
    }
}

// ---------------- node GEMM (m97 128x128, BK=32) ----------------
// EPI 0: relu -> bf16 store (ldc 256).
// EPI 2: f32 store outf = acc + bias + resid (ldc 256).
// EPI 3: bf16 store, NO relu, ldc 512 (Yab producer).
// GATHER3: A-row k 0..255 from ob, 256..511 from hb, 512..767 from aggb
//          (all [nf][256] bf16 contiguous); KPAD arg must be 768.
template<int EPI, bool GATHER3>
__global__ __launch_bounds__(256) void gemm_kernel(
    const unsigned short* __restrict__ A, const unsigned short* __restrict__ Wt,
    const float* __restrict__ bias, unsigned short* __restrict__ Cb, int KPAD,
    const float* __restrict__ resid, float* __restrict__ outf,
    const unsigned short* __restrict__ ob, const unsigned short* __restrict__ hb,
    const unsigned short* __restrict__ aggb) {
    __shared__ unsigned short As[128 * 32];
    __shared__ unsigned short Bs[128 * 32];
    int tid = threadIdx.x;
    int lane = tid & 63, w = tid >> 6;
    int wr = w >> 1, wc = w & 1;
    int blockRow = blockIdx.x * 128, colBase = blockIdx.y * 128;
    int l4 = lane >> 2;
    int seg = lane & 3;

    int ar0 = blockRow + w * 16 + l4;
    int ar1 = ar0 + 64;
    int br0 = colBase + w * 16 + l4;
    const unsigned short* pA0;
    const unsigned short* pA1;
    if (!GATHER3) {
        pA0 = A + (size_t)ar0 * KPAD + seg * 8;
        pA1 = A + (size_t)ar1 * KPAD + seg * 8;
    }
    const unsigned short* pB0 = Wt + (size_t)br0 * KPAD + seg * 8;
    const unsigned short* pB1 = pB0 + (size_t)64 * KPAD;

    unsigned short* ldsA = As + w * 512;
    unsigned short* ldsB = Bs + w * 512;

    f32x4 acc[4][4] = {};
    int lr = lane & 15, lq = lane >> 4;

    for (int k0 = 0; k0 < KPAD; k0 += 32) {
        if (GATHER3) {
            const unsigned short* src =
                (k0 < 256) ? ob : (k0 < 512) ? hb : aggb;
            int koff = (k0 & 255) + seg * 8;
            GLOAD_LDS16(src + (size_t)ar0 * 256 + koff, ldsA);
            GLOAD_LDS16(src + (size_t)ar1 * 256 + koff, ldsA + 2048);
        } else {
            GLOAD_LDS16(pA0 + k0, ldsA);
            GLOAD_LDS16(pA1 + k0, ldsA + 2048);
        }
        GLOAD_LDS16(pB0 + k0, ldsB);
        GLOAD_LDS16(pB1 + k0, ldsB + 2048);
        __syncthreads();
        bf16x8 a[4], b[4];
#pragma unroll
        for (int m = 0; m < 4; ++m)
            a[m] = *reinterpret_cast<const bf16x8*>(
                As + (wr * 64 + m * 16 + lr) * 32 + lq * 8);
#pragma unroll
        for (int n = 0; n < 4; ++n)
            b[n] = *reinterpret_cast<const bf16x8*>(
                Bs + (wc * 64 + n * 16 + lr) * 32 + lq * 8);
#pragma unroll
        for (int m = 0; m < 4; ++m)
#pragma unroll
            for (int n = 0; n < 4; ++n)
                acc[m][n] = __builtin_amdgcn_mfma_f32_16x16x32_bf16(
                    a[m], b[n], acc[m][n], 0, 0, 0);
        __syncthreads();
    }

    float bv[4];
#pragma unroll
    for (int n = 0; n < 4; ++n) bv[n] = bias[colBase + wc * 64 + n * 16 + lr];

#pragma unroll
    for (int m = 0; m < 4; ++m)
#pragma unroll
        for (int r = 0; r < 4; ++r) {
            int row = blockRow + wr * 64 + m * 16 + lq * 4 + r;
#pragma unroll
            for (int n = 0; n < 4; ++n) {
                int col = colBase + wc * 64 + n * 16 + lr;
                float v = acc[m][n][r] + bv[n];
                if (EPI == 2) {
                    outf[(size_t)row * 256 + col] =
                        v + resid[(size_t)row * 256 + col];
                } else if (EPI == 3) {
                    Cb[(size_t)row * 512 + col] = f2b(v);
                } else {
                    Cb[(size_t)row * 256 + col] = f2b(fmaxf(v, 0.f));
                }
            }
        }
}

__global__ void coordout_kernel(const float* __restrict__ x, const int* __restrict__ counts,
                                const float* __restrict__ csum, float* __restrict__ outc) {
    int idx = blockIdx.x * blockDim.x + threadIdx.x;
    if (idx >= TT * NN * 12) return;
    int n = (idx / 12) & (NN - 1);
    float cnt = (float)(counts[n] > 0 ? counts[n] : 1);
    outc[idx] = x[idx] + csum[idx] / cnt;
}

// ---------------- launch ----------------

extern "C" void kernel_launch(void* const* d_in, const int* in_sizes, int n_in,
                              void* d_out, int out_size, void* d_ws, size_t ws_size,
                              hipStream_t stream) {
    const float* x = (const float*)d_in[0];
    const float* h = (const float*)d_in[1];
    const float* others = (const float*)d_in[2];
    const float* We1 = (const float*)d_in[3];
    const float* be1 = (const float*)d_in[4];
    const float* We2 = (const float*)d_in[5];
    const float* be2 = (const float*)d_in[6];
    const float* Wn1 = (const float*)d_in[7];
    const float* bn1 = (const float*)d_in[8];
    const float* Wn2 = (const float*)d_in[9];
    const float* bn2 = (const float*)d_in[10];
    const float* Wc1 = (const float*)d_in[11];
    const float* bc1 = (const float*)d_in[12];
    const float* Wc2 = (const float*)d_in[13];
    const int* ei = (const int*)d_in[14];
    const int* rows = ei;
    const int* cols = ei + EE;

    char* wsb = (char*)d_ws;
    size_t off = 0;
    auto alloc = [&](size_t bytes) {
        void* p = wsb + off;
        off = (off + bytes + 255) & ~(size_t)255;
        return p;
    };
    const int TNH = TT * NN * HH;
    unsigned short* hb = (unsigned short*)alloc((size_t)TNH * 2);
    unsigned short* ob = (unsigned short*)alloc((size_t)TNH * 2);
    unsigned short* aggb = (unsigned short*)alloc((size_t)TNH * 2);
    unsigned short* Wabt = (unsigned short*)alloc(512 * 256 * 2);
    unsigned short* Wrt = (unsigned short*)alloc(256 * 32 * 2);
    unsigned short* We2t = (unsigned short*)alloc(256 * 256 * 2);
    unsigned short* Wn1t = (unsigned short*)alloc(256 * 768 * 2);
    unsigned short* Wn2t = (unsigned short*)alloc(256 * 256 * 2);
    unsigned short* Wc1t = (unsigned short*)alloc(256 * 256 * 2);
    float* bias512 = (float*)alloc(512 * 4);
    unsigned short* yab = (unsigned short*)alloc((size_t)TT * NN * 512 * 2);  // 21 MB
    float* aggf = (float*)alloc((size_t)TT * NN * 256 * 4);  // contiguous zero region:
    float* csum = (float*)alloc((size_t)TT * NN * 12 * 4);   // aggf | csum
    int* counts = (int*)alloc((size_t)2048 * 4);   // counts | cursor (zeroed together)
    int* cursor = (int*)alloc((size_t)2048 * 4);
    int* boff = (int*)alloc((size_t)2049 * 4);
    int* rs = (int*)alloc((size_t)EE * 4);
    int* cs = (int*)alloc((size_t)EE * 4);
    unsigned short* Z = (unsigned short*)alloc((size_t)TT * NN * 256 * 2);
    (void)ws_size;

    // ---- setup ----
    cvt2_bf16_kernel<<<2048, 256, 0, stream>>>(h, others, hb, ob, TNH);
    transpose_all_kernel<<<2082, 256, 0, stream>>>(
        We1, We2, Wn1, Wn2, Wc1, be1, Wabt, Wrt, We2t, Wn1t, Wn2t, Wc1t, bias512);
    zero_f32_kernel<<<16, 256, 0, stream>>>((float*)counts, 4096);  // counts+cursor
    count_kernel<<<EE / 256, 256, 0, stream>>>(rows, counts);
    scan_kernel<<<1, 256, 0, stream>>>(counts, boff);
    scatter_kernel<<<EE / 256, 256, 0, stream>>>(rows, cols, boff, cursor, rs, cs);
    zero_f32_kernel<<<2048, 256, 0, stream>>>(aggf, TT * NN * 256 + TT * NN * 12);

    float* houtf = (float*)d_out;
    float* coutf = (float*)d_out + (size_t)TT * NN * HH;

    // ---- Yab = h @ [We1a|We1b] + [be1|0]  -> bf16 [20480][512] ----
    gemm_kernel<3, false><<<dim3(TT * NN / 128, 4), 256, 0, stream>>>(
        hb, Wabt, bias512, yab, 256, nullptr, nullptr, nullptr, nullptr, nullptr);

    // ---- fused edge pipeline: all T, sorted edges, CSR epilogues ----
    edge_mega_kernel<<<TT * EE / 64, 256, 0, stream>>>(
        x, yab, Wrt, We2t, be2, Wc1t, bc1, Wc2, rs, cs, aggf, csum);

    // ---- node pipeline: agg -> bf16, then gather-GEMM (no node_in tensor) ----
    cvt_bf16_kernel<<<2048, 256, 0, stream>>>(aggf, aggb, TNH);
    gemm_kernel<0, true><<<dim3(TT * NN / 128, 2), 256, 0, stream>>>(
        nullptr, Wn1t, bn1, Z, 768, nullptr, nullptr, ob, hb, aggb);
    gemm_kernel<2, false><<<dim3(TT * NN / 128, 2), 256, 0, stream>>>(
        Z, Wn2t, bn2, nullptr, 256, h, houtf, nullptr, nullptr, nullptr);

    coordout_kernel<<<(TT * NN * 12 + 255) / 256, 256, 0, stream>>>(
        x, counts, csum, coutf);
}